// Round 2
// baseline (137.648 us; speedup 1.0000x reference)
//
#include <hip/hip_runtime.h>

// PQ embedding gather:
//   out[t, m*32 + j] = centroids[m, item_codes[ids[t], m], j]
// B*S = 102400 tokens, M = 8 code bytes, SUB = 32 floats, 256 centroids/byte.
//   ids:        int32   [B*S]
//   item_codes: int32   [(N+1)*8]    (32 MB, random-row gather, zero reuse)
//   centroids:  float32 [8*256*32]   (256 KB -- must stay L2-resident!)
//   out:        float32 [B*S*256]    (105 MB streaming write)
//
// R8: R7's staged structure + NONTEMPORAL output stores.
// Theory: 105 MB of write-allocate stores stream through 32 MB of L2 and
// continuously evict the 256 KB centroid table; every token then re-reads
// 1 KB of centroids as 8 random 128-B HBM segments (~105 MB of random
// reads) -- the missing 40 us between the ~19 us roofline and the ~60 us
// observed kernel. NT stores (no L2 allocate) keep centroids resident.
// NOTE: R6 tried nt stores and regressed, but R6 interleaved loads/stores
// per chunk, so in-order vmcnt retirement gated every chunk's loads on the
// previous chunk's (now slower-retiring) nt stores. R7's staging -- ALL
// loads issued before ANY store, stores dead-last -- removes that gating,
// so the R6 result does not transfer.
//   - nt loads on code rows kept (zero reuse; don't evict centroids).
//   - grid 3200, barrier-free, LDS-free (R7).

typedef float f4 __attribute__((ext_vector_type(4)));

#define M_BYTES 8
#define SUB_DIM 32
#define EMB     (M_BYTES * SUB_DIM)   // 256 floats per token
#define TPW     8                     // tokens per wave
#define WAVES   4
#define TOK_PER_BLOCK (TPW * WAVES)   // 32
#define BLOCK   256

__global__ __launch_bounds__(BLOCK) void ItemCodeLayer_30253749633338_kernel(
    const int*   __restrict__ ids,    // [B*S]
    const int*   __restrict__ codes,  // [(N+1)*M]
    const float* __restrict__ cent,   // [M*256*SUB]
    float*       __restrict__ out,    // [B*S*EMB]
    int n_tokens)
{
    const int tid  = threadIdx.x;
    const int l    = tid & 63;
    const int wave = __builtin_amdgcn_readfirstlane(tid >> 6);  // SGPR wave id
    const int lm   = l >> 3;          // code byte handled by this lane group
    const int l4   = l * 4;           // = lm*SUB_DIM + (l&7)*4, lane's out offset

    const float* centBase = cent + (size_t)lm * 256 * SUB_DIM + (l & 7) * 4;

    const int t0 = blockIdx.x * TOK_PER_BLOCK + wave * TPW;

    if (t0 + TPW <= n_tokens) {
        // Stage 1: 8 independent NT code gathers (random 32 B rows in 32 MB).
        int c[TPW];
        #pragma unroll
        for (int k = 0; k < TPW; ++k) {
            int id = ids[t0 + k];                       // wave-uniform -> s_load
            c[k] = __builtin_nontemporal_load(codes + (size_t)id * M_BYTES + lm);
        }
        // Stage 2: 8 centroid gathers (16 B/lane, 128-B row per 8-lane group).
        // These MUST hit L2 -- protecting them is the whole point of R8.
        f4 v[TPW];
        #pragma unroll
        for (int k = 0; k < TPW; ++k)
            v[k] = *reinterpret_cast<const f4*>(centBase + (size_t)c[k] * SUB_DIM);
        // Stage 3: 8 streaming NT stores (64 lanes x 16 B = contiguous 1 KB).
        // No L2 allocation -> centroid table stays resident.
        #pragma unroll
        for (int k = 0; k < TPW; ++k)
            __builtin_nontemporal_store(
                v[k], reinterpret_cast<f4*>(out + (size_t)(t0 + k) * EMB + l4));
    } else if (t0 < n_tokens) {
        // guarded tail (never taken at B*S = 102400 = 3200*32)
        #pragma unroll
        for (int k = 0; k < TPW; ++k) {
            int t = t0 + k;
            if (t < n_tokens) {
                int id  = ids[t];
                int cd  = codes[(size_t)id * M_BYTES + lm];
                f4 val  = *reinterpret_cast<const f4*>(centBase + (size_t)cd * SUB_DIM);
                *reinterpret_cast<f4*>(out + (size_t)t * EMB + l4) = val;
            }
        }
    }
}

extern "C" void kernel_launch(void* const* d_in, const int* in_sizes, int n_in,
                              void* d_out, int out_size, void* d_ws, size_t ws_size,
                              hipStream_t stream) {
    const int*   ids   = (const int*)  d_in[0];   // input_ids  [B*S] int32
    const int*   codes = (const int*)  d_in[1];   // item_codes [(N+1)*M] int32
    const float* cent  = (const float*)d_in[2];   // centroids  [M*256*SUB] float32
    float*       out   = (float*)      d_out;

    const int n_tokens = in_sizes[0];             // 102400 tokens
    const int grid = (n_tokens + TOK_PER_BLOCK - 1) / TOK_PER_BLOCK;   // 3200

    hipLaunchKernelGGL(ItemCodeLayer_30253749633338_kernel,
                       dim3(grid), dim3(BLOCK), 0, stream,
                       ids, codes, cent, out, n_tokens);
}